// Round 1
// baseline (505.098 us; speedup 1.0000x reference)
//
#include <hip/hip_runtime.h>
#include <hip/hip_bf16.h>
#include <math.h>

// Problem constants
#define BB 4
#define SS 2048
#define DD 1024
#define HH 16
#define DKK 64
#define MM (BB*SS)      // 8192
#define NN (HH*DKK)     // 1024

typedef short bf16x8 __attribute__((ext_vector_type(8)));
typedef unsigned short us8 __attribute__((ext_vector_type(8)));
typedef unsigned short us4 __attribute__((ext_vector_type(4)));
typedef float f32x4 __attribute__((ext_vector_type(4)));

__device__ __forceinline__ unsigned short f2bf(float f) {
  unsigned int u = __builtin_bit_cast(unsigned int, f);
  u += 0x7fffu + ((u >> 16) & 1u);
  return (unsigned short)(u >> 16);
}

__device__ __forceinline__ void gload16(const void* g, void* l) {
  __builtin_amdgcn_global_load_lds(
      (const __attribute__((address_space(1))) unsigned int*)g,
      (__attribute__((address_space(3))) unsigned int*)l, 16, 0, 0);
}

// ---- fp32 -> bf16 conversion (activations), 4 elems/thread ----
__global__ __launch_bounds__(256) void k_conv(const float* __restrict__ in,
                                              unsigned short* __restrict__ out) {
  int i = blockIdx.x * 256 + threadIdx.x;           // i < 2097152
  float4 v = ((const float4*)in)[i];
  us4 o;
  o[0] = f2bf(v.x); o[1] = f2bf(v.y); o[2] = f2bf(v.z); o[3] = f2bf(v.w);
  ((us4*)out)[i] = o;
}

// ---- pack per-head weight [H,D,DK] -> Wt[N=H*64+c][K=D] bf16 ----
__global__ __launch_bounds__(256) void k_pack_w(const float* __restrict__ w,
                                                unsigned short* __restrict__ wt) {
  int o = blockIdx.x * 256 + threadIdx.x;           // < 1048576
  int n = o >> 10, d = o & 1023;
  int h = n >> 6, c = n & 63;
  wt[o] = f2bf(w[(h * 1024 + d) * 64 + c]);
}

// ---- pack wo [K=H*DK][N=D] -> WoT[n][k] bf16 (transpose) ----
__global__ __launch_bounds__(256) void k_pack_wo(const float* __restrict__ w,
                                                 unsigned short* __restrict__ wt) {
  int o = blockIdx.x * 256 + threadIdx.x;
  int n = o >> 10, k = o & 1023;
  wt[o] = f2bf(w[k * 1024 + n]);
}

// ---- bf16 GEMM: C[M,1024] = A[M,1024] * Bt[1024,1024]^T, epilogue (acc+bias)*scale ----
// m97 structure: 128x128 tile, BK=32, 4 waves 2x2, global_load_lds width 16.
template<int OUT_BF16>
__global__ __launch_bounds__(256) void k_gemm(const unsigned short* __restrict__ A,
                                              const unsigned short* __restrict__ Bt,
                                              const float* __restrict__ bias,
                                              void* __restrict__ Cout,
                                              float scale) {
  __shared__ unsigned short As[128 * 32];
  __shared__ unsigned short Bs[128 * 32];
  const int tid = threadIdx.x;
  const int l = tid & 63, w = tid >> 6;
  const int wr = w >> 1, wc = w & 1;
  const int bx = blockIdx.x & 7;        // N/128 = 8
  const int by = blockIdx.x >> 3;       // M/128 = 64
  const long brow = (long)by * 128;
  const int bcol = bx * 128;
  const int lr = l & 15, lg = l >> 4;
  f32x4 acc[4][4] = {};

  for (int k0 = 0; k0 < 1024; k0 += 32) {
    __syncthreads();
#pragma unroll
    for (int i = 0; i < 2; ++i) {
      int idx = i * 256 + tid;
      int r = idx >> 2, ch = idx & 3;
      gload16(A + (brow + r) * 1024 + k0 + ch * 8, &As[(i * 256 + w * 64) * 8]);
      gload16(Bt + (long)(bcol + r) * 1024 + k0 + ch * 8, &Bs[(i * 256 + w * 64) * 8]);
    }
    __syncthreads();
    bf16x8 af[4], bfr[4];
#pragma unroll
    for (int m = 0; m < 4; ++m)
      af[m] = *(const bf16x8*)&As[(wr * 64 + m * 16 + lr) * 32 + lg * 8];
#pragma unroll
    for (int n = 0; n < 4; ++n)
      bfr[n] = *(const bf16x8*)&Bs[(wc * 64 + n * 16 + lr) * 32 + lg * 8];
#pragma unroll
    for (int m = 0; m < 4; ++m)
#pragma unroll
      for (int n = 0; n < 4; ++n)
        acc[m][n] = __builtin_amdgcn_mfma_f32_16x16x32_bf16(af[m], bfr[n], acc[m][n], 0, 0, 0);
  }

#pragma unroll
  for (int m = 0; m < 4; ++m) {
#pragma unroll
    for (int n = 0; n < 4; ++n) {
      int col = bcol + wc * 64 + n * 16 + lr;
      float bia = bias[col];
#pragma unroll
      for (int i = 0; i < 4; ++i) {
        long row = brow + wr * 64 + m * 16 + lg * 4 + i;
        float v = (acc[m][n][i] + bia) * scale;
        if (OUT_BF16) ((unsigned short*)Cout)[row * 1024 + col] = f2bf(v);
        else          ((float*)Cout)[row * 1024 + col] = v;
      }
    }
  }
}

// ---- transpose V_all [8192,1024] -> Vt [bh][c=64][s=2048] (bf16) ----
__global__ __launch_bounds__(256) void k_transpose_v(const unsigned short* __restrict__ V,
                                                     unsigned short* __restrict__ Vt) {
  __shared__ unsigned short tile[64][72];
  int bid = blockIdx.x;
  int bh = bid >> 5, st = bid & 31;
  int b = bh >> 4, h = bh & 15;
  int tid = threadIdx.x;
#pragma unroll
  for (int i = 0; i < 2; ++i) {
    int idx = i * 256 + tid;
    int r = idx >> 3, ch = idx & 7;
    us8 v = *(const us8*)&V[((long)(b * 2048 + st * 64 + r)) * 1024 + h * 64 + ch * 8];
#pragma unroll
    for (int j = 0; j < 8; ++j) tile[ch * 8 + j][r] = v[j];
  }
  __syncthreads();
#pragma unroll
  for (int i = 0; i < 2; ++i) {
    int idx = i * 256 + tid;
    int c = idx >> 3, ch = idx & 7;
    us8 v;
#pragma unroll
    for (int j = 0; j < 8; ++j) v[j] = tile[c][ch * 8 + j];
    *(us8*)&Vt[(long)bh * 131072 + (long)c * 2048 + st * 64 + ch * 8] = v;
  }
}

// ---- flash attention: Q pre-scaled by log2e/8; online softmax in exp2 domain ----
// Blocks: bh(64) x qtile(32). 4 waves, each owns 16 q-rows. KVBLK=64.
__global__ __launch_bounds__(256) void k_attn(const unsigned short* __restrict__ Q,
                                              const unsigned short* __restrict__ K,
                                              const unsigned short* __restrict__ Vt,
                                              unsigned short* __restrict__ AO) {
  __shared__ unsigned short Ks[64 * 64];
  __shared__ unsigned short Vs[64 * 64];
  __shared__ unsigned short Ps[4 * 16 * 64];
  const int tid = threadIdx.x;
  const int l = tid & 63, w = tid >> 6;
  const int lr = l & 15, lg = l >> 4;
  const int bid = blockIdx.x;
  const int bh = bid >> 5, qt = bid & 31;
  const int b = bh >> 4, h = bh & 15;
  const unsigned short* Qb = Q + (long)b * 2048 * 1024 + h * 64;
  const unsigned short* Kb = K + (long)b * 2048 * 1024 + h * 64;
  const unsigned short* Vb = Vt + (long)bh * 64 * 2048;

  bf16x8 qf[2];
  {
    long qrow = qt * 64 + w * 16 + lr;
    qf[0] = *(const bf16x8*)&Qb[qrow * 1024 + lg * 8];
    qf[1] = *(const bf16x8*)&Qb[qrow * 1024 + 32 + lg * 8];
  }
  float mi[4], li[4];
  f32x4 o[4] = {};
#pragma unroll
  for (int i = 0; i < 4; ++i) { mi[i] = -1e30f; li[i] = 0.f; }

  char* Pw = (char*)Ps + w * 2048;

  for (int t0 = 0; t0 < 2048; t0 += 64) {
    __syncthreads();
#pragma unroll
    for (int i = 0; i < 2; ++i) {
      int idx = i * 256 + tid;
      int r = idx >> 3, ch = idx & 7;
      int sw = (ch * 16) ^ ((r & 7) << 4);
      gload16((const char*)(Kb + (long)(t0 + r) * 1024) + sw, &Ks[(i * 256 + w * 64) * 8]);
      gload16((const char*)(Vb + (long)r * 2048 + t0) + sw, &Vs[(i * 256 + w * 64) * 8]);
    }
    __syncthreads();

    // QK^T: s[n][i] = S[q=4*lg+i][t = n*16+lr]  (already *log2e/8 via Q scaling)
    f32x4 s[4];
#pragma unroll
    for (int n = 0; n < 4; ++n) {
      int row = n * 16 + lr;
      const char* kr = (const char*)Ks + row * 128;
      bf16x8 kb0 = *(const bf16x8*)(kr + ((lg * 16) ^ ((row & 7) << 4)));
      bf16x8 kb1 = *(const bf16x8*)(kr + ((64 + lg * 16) ^ ((row & 7) << 4)));
      f32x4 z = {0.f, 0.f, 0.f, 0.f};
      z = __builtin_amdgcn_mfma_f32_16x16x32_bf16(qf[0], kb0, z, 0, 0, 0);
      s[n] = __builtin_amdgcn_mfma_f32_16x16x32_bf16(qf[1], kb1, z, 0, 0, 0);
    }

    // online softmax (row groups of 16 lanes share a q-row set)
    float pm[4];
#pragma unroll
    for (int i = 0; i < 4; ++i)
      pm[i] = fmaxf(fmaxf(s[0][i], s[1][i]), fmaxf(s[2][i], s[3][i]));
#pragma unroll
    for (int i = 0; i < 4; ++i) {
      pm[i] = fmaxf(pm[i], __shfl_xor(pm[i], 1));
      pm[i] = fmaxf(pm[i], __shfl_xor(pm[i], 2));
      pm[i] = fmaxf(pm[i], __shfl_xor(pm[i], 4));
      pm[i] = fmaxf(pm[i], __shfl_xor(pm[i], 8));
    }
    float p[4][4];
#pragma unroll
    for (int i = 0; i < 4; ++i) {
      float mn = fmaxf(mi[i], pm[i]);
      float fsc = exp2f(mi[i] - mn);
      mi[i] = mn;
      float ps = 0.f;
#pragma unroll
      for (int n = 0; n < 4; ++n) { p[n][i] = exp2f(s[n][i] - mn); ps += p[n][i]; }
      li[i] = li[i] * fsc + ps;
#pragma unroll
      for (int n = 0; n < 4; ++n) o[n][i] *= fsc;
    }

    // write P (bf16) to per-wave LDS region, swizzled rows
#pragma unroll
    for (int n = 0; n < 4; ++n)
#pragma unroll
      for (int i = 0; i < 4; ++i) {
        int q = lg * 4 + i;
        int byo = q * 128 + (((n * 16 + lr) * 2) ^ ((q & 7) << 4));
        *(unsigned short*)(Pw + byo) = f2bf(p[n][i]);
      }

    // PV: O[q][c] += P[q][t] * V[t][c]
    bf16x8 pa[2];
#pragma unroll
    for (int tk = 0; tk < 2; ++tk)
      pa[tk] = *(const bf16x8*)(Pw + lr * 128 + ((tk * 64 + lg * 16) ^ ((lr & 7) << 4)));
#pragma unroll
    for (int n = 0; n < 4; ++n) {
      int row = n * 16 + lr;
      const char* vr = (const char*)Vs + row * 128;
#pragma unroll
      for (int tk = 0; tk < 2; ++tk) {
        bf16x8 vb = *(const bf16x8*)(vr + ((tk * 64 + lg * 16) ^ ((row & 7) << 4)));
        o[n] = __builtin_amdgcn_mfma_f32_16x16x32_bf16(pa[tk], vb, o[n], 0, 0, 0);
      }
    }
  }

  // finalize: reduce l across the 16-lane row group, divide, store bf16
#pragma unroll
  for (int i = 0; i < 4; ++i) {
    li[i] += __shfl_xor(li[i], 1);
    li[i] += __shfl_xor(li[i], 2);
    li[i] += __shfl_xor(li[i], 4);
    li[i] += __shfl_xor(li[i], 8);
    li[i] = 1.f / li[i];
  }
#pragma unroll
  for (int n = 0; n < 4; ++n)
#pragma unroll
    for (int i = 0; i < 4; ++i) {
      long row = (long)b * 2048 + qt * 64 + w * 16 + lg * 4 + i;
      int col = h * 64 + n * 16 + lr;
      AO[row * 1024 + col] = f2bf(o[n][i] * li[i]);
    }
}

extern "C" void kernel_launch(void* const* d_in, const int* in_sizes, int n_in,
                              void* d_out, int out_size, void* d_ws, size_t ws_size,
                              hipStream_t stream) {
  (void)in_sizes; (void)n_in; (void)out_size; (void)ws_size;
  const float* q_in = (const float*)d_in[0];
  const float* k_in = (const float*)d_in[1];
  const float* v_in = (const float*)d_in[2];
  const float* wq   = (const float*)d_in[3];
  const float* bq   = (const float*)d_in[4];
  const float* wk   = (const float*)d_in[5];
  const float* bk   = (const float*)d_in[6];
  const float* wv   = (const float*)d_in[7];
  const float* bv   = (const float*)d_in[8];
  const float* wo   = (const float*)d_in[9];
  const float* bo   = (const float*)d_in[10];

  char* ws = (char*)d_ws;
  const size_t SZA = (size_t)8192 * 1024 * 2;   // 16 MiB per [8192,1024] bf16
  unsigned short* Aq  = (unsigned short*)(ws);
  unsigned short* Ak  = (unsigned short*)(ws + SZA);
  unsigned short* Av  = (unsigned short*)(ws + 2 * SZA);
  unsigned short* Qa  = (unsigned short*)(ws + 3 * SZA);
  unsigned short* Ka  = (unsigned short*)(ws + 4 * SZA);
  unsigned short* Va  = (unsigned short*)(ws + 5 * SZA);
  unsigned short* Wqt = (unsigned short*)(ws + 6 * SZA);
  unsigned short* Wkt = Wqt + 1048576;
  unsigned short* Wvt = Wkt + 1048576;
  unsigned short* Wot = Wvt + 1048576;
  unsigned short* Vtr = Ak;   // Ak dead after K projection GEMM
  unsigned short* AO  = Aq;   // Aq dead after Q projection GEMM

  const float QSCALE = 0.1803368801111204f;  // log2(e)/8 -> exp2-domain softmax

  k_conv<<<8192, 256, 0, stream>>>(q_in, Aq);
  k_conv<<<8192, 256, 0, stream>>>(k_in, Ak);
  k_conv<<<8192, 256, 0, stream>>>(v_in, Av);
  k_pack_w<<<4096, 256, 0, stream>>>(wq, Wqt);
  k_pack_w<<<4096, 256, 0, stream>>>(wk, Wkt);
  k_pack_w<<<4096, 256, 0, stream>>>(wv, Wvt);
  k_pack_wo<<<4096, 256, 0, stream>>>(wo, Wot);

  k_gemm<1><<<512, 256, 0, stream>>>(Aq, Wqt, bq, Qa, QSCALE);
  k_gemm<1><<<512, 256, 0, stream>>>(Ak, Wkt, bk, Ka, 1.0f);
  k_gemm<1><<<512, 256, 0, stream>>>(Av, Wvt, bv, Va, 1.0f);

  k_transpose_v<<<2048, 256, 0, stream>>>(Va, Vtr);
  k_attn<<<2048, 256, 0, stream>>>(Qa, Ka, Vtr, AO);

  k_gemm<0><<<512, 256, 0, stream>>>(AO, Wot, bo, (float*)d_out, 1.0f);
}